// Round 1
// baseline (40.998 us; speedup 1.0000x reference)
//
#include <hip/hip_runtime.h>

#define PNUM 1024
#define NB   128

// Kernel 1: one block handles (batch b, 64 consecutive shifts).
// block = 256 threads = 64 shifts x 4 j-quarters. Each thread accumulates
// the smooth-L1 cost of its shift over 256 j values, then we reduce.
__global__ __launch_bounds__(256) void poly_cost_kernel(
    const float* __restrict__ pred, const float* __restrict__ gt,
    float* __restrict__ block_min) {
  __shared__ float2 pred_s[PNUM];        // 8 KB
  __shared__ float2 gt_s[2 * PNUM];      // 16 KB (duplicated: no modulo)
  __shared__ float partial[256];         // 1 KB

  const int b     = blockIdx.x >> 4;     // 16 chunks per batch
  const int chunk = blockIdx.x & 15;
  const int t     = threadIdx.x;

  const float2* pred2 = (const float2*)(pred + (size_t)b * PNUM * 2);
  const float2* gt2   = (const float2*)(gt   + (size_t)b * PNUM * 2);

  // Stage inputs into LDS (coalesced float2 loads).
  #pragma unroll
  for (int k = t; k < PNUM; k += 256) pred_s[k] = pred2[k];
  #pragma unroll
  for (int k = t; k < 2 * PNUM; k += 256) gt_s[k] = gt2[k & (PNUM - 1)];
  __syncthreads();

  const int il = t & 63;          // shift within chunk (lane id)
  const int jq = t >> 6;          // j-quarter (wave id) -> pred reads wave-uniform
  const int i  = chunk * 64 + il; // global shift
  const int j0 = jq * 256;

  // sl1(d) = 0.5*m^2 + (|d| - m), m = min(|d|,1)
  // accA = sum m^2 ; accB = sum |d| ; accC = sum m
  float accA = 0.f, accB = 0.f, accC = 0.f;
  const int gbase = i + j0;
  #pragma unroll 8
  for (int jj = 0; jj < 256; ++jj) {
    float2 p = pred_s[j0 + jj];
    float2 g = gt_s[gbase + jj];
    float dx = p.x - g.x;
    float dy = p.y - g.y;
    float ax = fabsf(dx), ay = fabsf(dy);
    float mx = fminf(ax, 1.0f), my = fminf(ay, 1.0f);
    accA = fmaf(mx, mx, accA);
    accA = fmaf(my, my, accA);
    accB += ax + ay;
    accC += mx + my;
  }
  float acc = fmaf(0.5f, accA, accB - accC);

  // Reduce the 4 j-quarters per shift: threads t, t+64, t+128, t+192 share i.
  partial[t] = acc;
  __syncthreads();
  if (t < 64) {  // wave 0
    float tot = partial[t] + partial[t + 64] + partial[t + 128] + partial[t + 192];
    float dis = tot * (1.0f / PNUM);
    // min over the 64 shifts of this block (full-wave butterfly)
    #pragma unroll
    for (int off = 32; off; off >>= 1)
      dis = fminf(dis, __shfl_xor(dis, off));
    if (t == 0) block_min[blockIdx.x] = dis;
  }
}

// Kernel 2: per-batch min over its 16 block-mins, then mean over 128 batches.
__global__ __launch_bounds__(128) void poly_reduce_kernel(
    const float* __restrict__ block_min, float* __restrict__ out) {
  const int b = threadIdx.x;  // one thread per batch
  float m = block_min[b * 16];
  #pragma unroll
  for (int c = 1; c < 16; ++c) m = fminf(m, block_min[b * 16 + c]);
  // sum across 128 threads (2 waves)
  #pragma unroll
  for (int off = 32; off; off >>= 1) m += __shfl_xor(m, off);
  __shared__ float wsum[2];
  if ((b & 63) == 0) wsum[b >> 6] = m;
  __syncthreads();
  if (b == 0) out[0] = (wsum[0] + wsum[1]) * (1.0f / NB);
}

extern "C" void kernel_launch(void* const* d_in, const int* in_sizes, int n_in,
                              void* d_out, int out_size, void* d_ws, size_t ws_size,
                              hipStream_t stream) {
  const float* pred = (const float*)d_in[0];
  const float* gt   = (const float*)d_in[1];
  float* out        = (float*)d_out;
  float* block_min  = (float*)d_ws;  // 2048 floats = 8 KB

  poly_cost_kernel<<<NB * 16, 256, 0, stream>>>(pred, gt, block_min);
  poly_reduce_kernel<<<1, 128, 0, stream>>>(block_min, out);
}

// Round 3
// 29.318 us; speedup vs baseline: 1.3984x; 1.3984x over previous
//
#include <hip/hip_runtime.h>

#define PNUM 1024
#define NB   128
// padded LDS index: +1 word every 4 elements -> lane banks 5*sslot mod 32 (all distinct)
#define PAD(k) ((k) + ((k) >> 2))

typedef _Float16 h2 __attribute__((ext_vector_type(2)));

// smooth-L1 identity: sl1(d) = m*(|d| - 0.5m), m = min(|d|,1)
// 5 packed ops: sub, abs, min, fma, fma -- x and y coords together.
#define SL1(acc, p, g) do {                               \
    h2 d_ = (p) - (g);                                    \
    h2 a_ = __builtin_elementwise_abs(d_);                \
    h2 m_ = __builtin_elementwise_min(a_, one2);          \
    h2 t_ = __builtin_elementwise_fma(m_, nh2, a_);       \
    (acc) = __builtin_elementwise_fma(m_, t_, (acc)); } while (0)

static __device__ __forceinline__ h2 to_h2(float2 f) {
  h2 r; r.x = (_Float16)f.x; r.y = (_Float16)f.y; return r;
}

// One block = (batch b, 64 consecutive shifts). 256 threads =
// 16 shift-slots (4 consecutive shifts each, rolling gt window) x 16 j-slots (64 j each).
__global__ __launch_bounds__(256) void poly_cost_kernel(
    const float* __restrict__ pred, const float* __restrict__ gt,
    float* __restrict__ block_min) {
  __shared__ h2    pred_s[1280];      // PAD(1023)=1278 -> 5.0 KB
  __shared__ h2    gt_s[1360];        // PAD(1087)=1358 -> 5.3 KB
  __shared__ float partial[16][64];   // 4 KB   (total ~14.3 KB -> 8 blocks/CU)

  const int b     = blockIdx.x >> 4;
  const int chunk = blockIdx.x & 15;
  const int t     = threadIdx.x;

  const float2* pred2 = (const float2*)(pred + (size_t)b * (PNUM * 2));
  const float2* gt2   = (const float2*)(gt   + (size_t)b * (PNUM * 2));

  // Stage fp32 -> packed fp16 into padded LDS.
  #pragma unroll
  for (int k = t; k < PNUM; k += 256)
    pred_s[PAD(k)] = to_h2(pred2[k]);
  const int gb = chunk * 64;
  for (int k = t; k < 1088; k += 256)           // only [chunk*64, chunk*64+1087] needed
    gt_s[PAD(k)] = to_h2(gt2[(gb + k) & (PNUM - 1)]);
  __syncthreads();

  const int sslot = t & 15;            // 4 consecutive shifts: i0 = chunk*64 + 4*sslot
  const int jslot = t >> 4;            // 64 consecutive j:   j0 = 64*jslot
  const int kbase = sslot * 4 + jslot * 64;   // gt element index at (s=0, jj=0)
  int A = PAD(kbase);                  // kbase % 4 == 0 -> pad offsets are compile-time
  int P = PAD(jslot * 64);

  const h2 one2 = { (_Float16)1.0f,  (_Float16)1.0f };
  const h2 nh2  = { (_Float16)-0.5f, (_Float16)-0.5f };
  h2 acc0 = { (_Float16)0.0f, (_Float16)0.0f };
  h2 acc1 = acc0, acc2 = acc0, acc3 = acc0;

  // rolling window: w holds gt elements kbase+jj .. +3
  h2 w0 = gt_s[A], w1 = gt_s[A + 1], w2 = gt_s[A + 2];

  for (int g = 0; g < 16; ++g) {       // 16 groups x 4 jj = 64 j per thread
    h2 p0 = pred_s[P];
    h2 w3 = gt_s[A + 3];               // element kbase+jj+3
    SL1(acc0, p0, w0); SL1(acc1, p0, w1); SL1(acc2, p0, w2); SL1(acc3, p0, w3);
    h2 p1 = pred_s[P + 1];
    h2 n0 = gt_s[A + 5];               // element +4 -> padded +5
    SL1(acc0, p1, w1); SL1(acc1, p1, w2); SL1(acc2, p1, w3); SL1(acc3, p1, n0);
    h2 p2 = pred_s[P + 2];
    h2 n1 = gt_s[A + 6];               // element +5
    SL1(acc0, p2, w2); SL1(acc1, p2, w3); SL1(acc2, p2, n0); SL1(acc3, p2, n1);
    h2 p3 = pred_s[P + 3];
    h2 n2 = gt_s[A + 7];               // element +6
    SL1(acc0, p3, w3); SL1(acc1, p3, n0); SL1(acc2, p3, n1); SL1(acc3, p3, n2);
    w0 = n0; w1 = n1; w2 = n2;
    A += 5; P += 5;                    // 4 elements + 1 pad word
  }

  // flush fp16 accumulators to fp32 partials: partial[jslot][local_shift]
  {
    const int ls = sslot * 4;
    partial[jslot][ls + 0] = (float)acc0.x + (float)acc0.y;
    partial[jslot][ls + 1] = (float)acc1.x + (float)acc1.y;
    partial[jslot][ls + 2] = (float)acc2.x + (float)acc2.y;
    partial[jslot][ls + 3] = (float)acc3.x + (float)acc3.y;
  }
  __syncthreads();

  if (t < 64) {                        // wave 0: sum 16 j-slot partials per shift
    float s = 0.0f;
    #pragma unroll
    for (int q = 0; q < 16; ++q) s += partial[q][t];
    float dis = s * (1.0f / 1024.0f);
    #pragma unroll
    for (int off = 32; off; off >>= 1)
      dis = fminf(dis, __shfl_xor(dis, off));
    if (t == 0) block_min[blockIdx.x] = dis;
  }
}

// Kernel 2: per-batch min over 16 block-mins, then mean over 128 batches.
__global__ __launch_bounds__(128) void poly_reduce_kernel(
    const float* __restrict__ block_min, float* __restrict__ out) {
  const int b = threadIdx.x;
  float m = block_min[b * 16];
  #pragma unroll
  for (int c = 1; c < 16; ++c) m = fminf(m, block_min[b * 16 + c]);
  #pragma unroll
  for (int off = 32; off; off >>= 1) m += __shfl_xor(m, off);
  __shared__ float wsum[2];
  if ((b & 63) == 0) wsum[b >> 6] = m;
  __syncthreads();
  if (b == 0) out[0] = (wsum[0] + wsum[1]) * (1.0f / NB);
}

extern "C" void kernel_launch(void* const* d_in, const int* in_sizes, int n_in,
                              void* d_out, int out_size, void* d_ws, size_t ws_size,
                              hipStream_t stream) {
  const float* pred = (const float*)d_in[0];
  const float* gt   = (const float*)d_in[1];
  float* out        = (float*)d_out;
  float* block_min  = (float*)d_ws;   // 2048 floats

  poly_cost_kernel<<<NB * 16, 256, 0, stream>>>(pred, gt, block_min);
  poly_reduce_kernel<<<1, 128, 0, stream>>>(block_min, out);
}